// Round 14
// baseline (30.073 us; speedup 1.0000x reference)
//
#include <hip/hip_runtime.h>

typedef float f2 __attribute__((ext_vector_type(2)));   // complex (re, im)

constexpr int NQ   = 10;
constexpr int CDIM = 768;
constexpr int NL   = 3;
constexpr int NR   = 8;    // reg bits 6..8; bit 9 = wave parity (wire 0)

// ---------- cross-lane primitives ----------

template<int CTRL>
__device__ __forceinline__ float dppmov(float x) {
    return __int_as_float(__builtin_amdgcn_update_dpp(
        __float_as_int(x), __float_as_int(x), CTRL, 0xF, 0xF, true));
}

template<int MASK>
__device__ __forceinline__ float lxor(float x, int lane) {
    static_assert(MASK == 1 || MASK == 2 || MASK == 4 || MASK == 8, "");
    if constexpr (MASK == 1)      return dppmov<0xB1>(x);   // quad_perm [1,0,3,2]
    else if constexpr (MASK == 2) return dppmov<0x4E>(x);   // quad_perm [2,3,0,1]
    else if constexpr (MASK == 4) {
        const float a = dppmov<0x104>(x);   // row_shl:4 -> src[i+4] (bit2=0)
        const float b = dppmov<0x114>(x);   // row_shr:4 -> src[i-4] (bit2=1)
        return ((lane >> 2) & 1) ? b : a;
    }
    else                          return dppmov<0x128>(x);  // row_ror:8 == xor8
}

template<int B>
__device__ __forceinline__ void swap2(float x, float& lo, float& hi) {
    const unsigned xu = __float_as_uint(x);
#if __has_builtin(__builtin_amdgcn_permlane16_swap) && __has_builtin(__builtin_amdgcn_permlane32_swap)
    if constexpr (B == 4) {
        auto r = __builtin_amdgcn_permlane16_swap(xu, xu, false, false);
        lo = __uint_as_float(r[0]); hi = __uint_as_float(r[1]);
    } else {
        auto r = __builtin_amdgcn_permlane32_swap(xu, xu, false, false);
        lo = __uint_as_float(r[0]); hi = __uint_as_float(r[1]);
    }
#else
    float d, s;
    if constexpr (B == 4)
        asm("v_mov_b32 %0, %2\n\tv_mov_b32 %1, %2\n\ts_nop 1\n\t"
            "v_permlane16_swap_b32 %0, %1" : "=&v"(d), "=&v"(s) : "v"(x));
    else
        asm("v_mov_b32 %0, %2\n\tv_mov_b32 %1, %2\n\ts_nop 1\n\t"
            "v_permlane32_swap_b32 %0, %1" : "=&v"(d), "=&v"(s) : "v"(x));
    lo = d; hi = s;
#endif
}

__device__ __forceinline__ float wave_sum(float v) {
    v += dppmov<0xB1>(v);
    v += dppmov<0x4E>(v);
    v += dppmov<0x141>(v);   // row_half_mirror = xor7 (bits 0-1 uniform)
    v += dppmov<0x140>(v);   // row_mirror = xor15
    float lo, hi;
    swap2<4>(v, lo, hi); v = lo + hi;
    swap2<5>(v, lo, hi); v = lo + hi;
    return v;
}

// ---------- complex helpers ----------

__device__ __forceinline__ f2 swapneg(f2 b) { f2 r; r.x = -b.y; r.y = b.x; return r; }
__device__ __forceinline__ f2 cmul(f2 a, f2 b) { return b * a.x + swapneg(b) * a.y; }
__device__ __forceinline__ f2 cfma(f2 a, f2 b, f2 acc) { return acc + b * a.x + swapneg(b) * a.y; }

// ---------- 1-qubit gate on LOCAL bit B (0..8) ----------

template<int B>
__device__ __forceinline__ void gate_bit(f2 (&v)[NR], int lane,
                                         f2 g00, f2 g01, f2 g10, f2 g11) {
    static_assert(B <= 8, "");
    if constexpr (B >= 6) {
        constexpr int rb = B - 6;
#pragma unroll
        for (int p = 0; p < NR / 2; ++p) {
            const int r0 = ((p >> rb) << (rb + 1)) | (p & ((1 << rb) - 1));
            const int r1 = r0 | (1 << rb);
            const f2 a0 = v[r0], a1 = v[r1];
            v[r0] = cfma(g01, a1, cmul(g00, a0));
            v[r1] = cfma(g11, a1, cmul(g10, a0));
        }
    } else if constexpr (B >= 4) {
        const bool hb = (lane >> B) & 1;
        const f2 A  = hb ? g10 : g00;
        const f2 Bc = hb ? g11 : g01;
#pragma unroll
        for (int r = 0; r < NR; ++r) {
            float lx, hx, ly, hy;
            swap2<B>(v[r].x, lx, hx);
            swap2<B>(v[r].y, ly, hy);
            f2 lo; lo.x = lx; lo.y = ly;
            f2 hi; hi.x = hx; hi.y = hy;
            v[r] = cfma(Bc, hi, cmul(A, lo));
        }
    } else {
        const bool hb = (lane >> B) & 1;
        const f2 cO = hb ? g11 : g00;
        const f2 cP = hb ? g10 : g01;
#pragma unroll
        for (int r = 0; r < NR; ++r) {
            f2 p;
            p.x = lxor<(1 << B)>(v[r].x, lane);
            p.y = lxor<(1 << B)>(v[r].y, lane);
            v[r] = cfma(cP, p, cmul(cO, v[r]));
        }
    }
}

template<int BT>
__device__ __forceinline__ float partner(float x, int lane) {
    if constexpr (BT >= 4) {
        float lo, hi; swap2<BT>(x, lo, hi);
        return ((lane >> BT) & 1) ? lo : hi;
    } else return lxor<(1 << BT)>(x, lane);
}

// ---------- CNOT (bit 9 = wave, 6..8 = reg, 0..5 = lane) ----------

template<int BC, int BT>
__device__ __forceinline__ void cnot(f2 (&v)[NR], int lane, int hs,
                                     f2* mybuf, const f2* pbuf) {
    if constexpr (BC == 9) {                      // wave control: hs=1 local flip
        if (hs) {
            if constexpr (BT >= 6) {
                constexpr int rt = BT - 6;
#pragma unroll
                for (int p = 0; p < NR / 2; ++p) {
                    const int r0 = ((p >> rt) << (rt + 1)) | (p & ((1 << rt) - 1));
                    const int r1 = r0 | (1 << rt);
                    const f2 t = v[r0]; v[r0] = v[r1]; v[r1] = t;
                }
            } else {
#pragma unroll
                for (int r = 0; r < NR; ++r) {
                    f2 n;
                    n.x = partner<BT>(v[r].x, lane);
                    n.y = partner<BT>(v[r].y, lane);
                    v[r] = n;
                }
            }
        }
    } else if constexpr (BT == 9) {               // wave target, lane control
        static_assert(BC < 6, "");
#pragma unroll
        for (int r = 0; r < NR; ++r) mybuf[r * 64 + lane] = v[r];
        __syncthreads();
        const bool c = (lane >> BC) & 1;
#pragma unroll
        for (int r = 0; r < NR; ++r) {
            const f2 pv = pbuf[r * 64 + lane];
            v[r] = c ? pv : v[r];
        }
        __syncthreads();
    } else if constexpr (BC >= 6 && BT >= 6) {
        constexpr int rc = BC - 6, rt = BT - 6;
#pragma unroll
        for (int r = 0; r < NR; ++r)
            if (((r >> rc) & 1) && !((r >> rt) & 1)) {
                const int r1 = r | (1 << rt);
                const f2 t = v[r]; v[r] = v[r1]; v[r1] = t;
            }
    } else if constexpr (BC >= 6) {               // reg control, lane target
        constexpr int rc = BC - 6;
#pragma unroll
        for (int r = 0; r < NR; ++r)
            if ((r >> rc) & 1) {
                f2 n;
                n.x = partner<BT>(v[r].x, lane);
                n.y = partner<BT>(v[r].y, lane);
                v[r] = n;
            }
    } else if constexpr (BT >= 6) {               // lane control, reg target
        constexpr int rt = BT - 6;
        const bool c = (lane >> BC) & 1;
#pragma unroll
        for (int p = 0; p < NR / 2; ++p) {
            const int r0 = ((p >> rt) << (rt + 1)) | (p & ((1 << rt) - 1));
            const int r1 = r0 | (1 << rt);
            const f2 a = v[r0], b = v[r1];
            v[r0] = c ? b : a;
            v[r1] = c ? a : b;
        }
    } else {                                      // both lane
        const bool c = (lane >> BC) & 1;
#pragma unroll
        for (int r = 0; r < NR; ++r) {
            f2 n;
            n.x = c ? partner<BT>(v[r].x, lane) : v[r].x;
            n.y = c ? partner<BT>(v[r].y, lane) : v[r].y;
            v[r] = n;
        }
    }
}

// ---------- layer drivers ----------

// Rot on wire 0 (= wave bit): cross-wave exchange
__device__ __forceinline__ void rot_wave_gate(f2 (&v)[NR], int lane, int hs,
                                              f2* mybuf, const f2* pbuf,
                                              const float4* g) {
    const float4 p0 = g[0];
    const float4 p1 = g[1];
    f2 g00 = {p0.x, p0.y}, g01 = {p0.z, p0.w};
    f2 g10 = {p1.x, p1.y}, g11 = {p1.z, p1.w};
    const f2 cO = hs ? g11 : g00;
    const f2 cP = hs ? g10 : g01;
#pragma unroll
    for (int r = 0; r < NR; ++r) mybuf[r * 64 + lane] = v[r];
    __syncthreads();
#pragma unroll
    for (int r = 0; r < NR; ++r) {
        const f2 pv = pbuf[r * 64 + lane];
        v[r] = cfma(cP, pv, cmul(cO, v[r]));
    }
    __syncthreads();
}

template<int Q = 1>
__device__ __forceinline__ void rot_layer_rest(f2 (&v)[NR], int lane,
                                               const float4* g /*LDS [NQ][2]*/) {
    if constexpr (Q < NQ) {
        const float4 p0 = g[Q * 2];
        const float4 p1 = g[Q * 2 + 1];
        f2 g00 = {p0.x, p0.y}, g01 = {p0.z, p0.w};
        f2 g10 = {p1.x, p1.y}, g11 = {p1.z, p1.w};
        gate_bit<9 - Q>(v, lane, g00, g01, g10, g11);
        rot_layer_rest<Q + 1>(v, lane, g);
    }
}

template<int I = 0>
__device__ __forceinline__ void cnot_ring1(f2 (&v)[NR], int lane, int hs,
                                           f2* mybuf, const f2* pbuf) {
    if constexpr (I < NQ) {
        cnot<9 - I, 9 - ((I + 2) % NQ)>(v, lane, hs, mybuf, pbuf);
        cnot_ring1<I + 1>(v, lane, hs, mybuf, pbuf);
    }
}

// ---------- ring-2 absorbed measurement ----------
constexpr unsigned ring2_mask(int w) {
    unsigned M[NQ] = {};
    for (int i = 0; i < NQ; ++i) M[i] = 1u << (9 - i);
    for (int i = 0; i < NQ; ++i) M[(i + 3) % NQ] ^= M[i];
    return M[w];
}

template<unsigned MR>
__device__ __forceinline__ float regsum8(const float (&pr)[NR]) {
    float s = 0.f;
#pragma unroll
    for (int r = 0; r < NR; ++r)
        s = (__builtin_popcount((unsigned)r & MR) & 1) ? s - pr[r] : s + pr[r];
    return s;
}

template<int W = 0>
__device__ __forceinline__ void measure_all(const float (&pr)[NR], int lane, int hs,
                                            float (&ev)[NQ]) {
    if constexpr (W < NQ) {
        constexpr unsigned m  = ring2_mask(W);
        constexpr unsigned mr = (m >> 6) & 0x7u;   // reg bits 6..8
        constexpr unsigned mw = (m >> 9) & 0x1u;   // wave bit 9
        constexpr unsigned ml = m & 63u;           // lane bits
        float s = regsum8<mr>(pr);
        unsigned par = 0;
        if constexpr (ml != 0) par = (unsigned)(__popc(lane & (int)ml) & 1);
        if constexpr (mw != 0) par ^= (unsigned)hs;
        if constexpr (ml != 0 || mw != 0)
            s = __uint_as_float(__float_as_uint(s) ^ (par << 31));
        ev[W] = wave_sum(s);
        measure_all<W + 1>(pr, lane, hs, ev);
    }
}

// ---------- main kernel: 2 waves per sample, 1 sample per block ----------

__global__ __launch_bounds__(128, 4) void qembed(
    const float* __restrict__ z,     // (B, CDIM)
    const float* __restrict__ Win,   // (CDIM, NQ)
    const float* __restrict__ bin,   // (NQ)
    const float* __restrict__ wts,   // (NL, NQ, 3)
    const float* __restrict__ Wout,  // (NQ, CDIM)
    const float* __restrict__ bout,  // (CDIM)
    float* __restrict__ out)         // (B, CDIM)
{
    __shared__ float4 gl4[NL][NQ][2];   // gate matrices (960 B)
    __shared__ f2 xch[2][NR * 64];      // 8 KB exchange
    __shared__ float sev[2][NQ];

    const int wave = threadIdx.x >> 6;     // 0/1 = index bit 9 (wire 0)
    const int lane = threadIdx.x & 63;
    const int hs   = wave;
    const int samp = blockIdx.x;
    f2* mybuf      = xch[wave];
    const f2* pbuf = xch[wave ^ 1];

    // ---- 30 threads build all gate matrices once per block ----
    if (threadIdx.x < NL * NQ) {
        const int li = threadIdx.x / NQ, q = threadIdx.x % NQ;
        const float* wp = wts + (li * NQ + q) * 3;
        const float phi = wp[0], th = wp[1], om = wp[2];
        float st, ct, sA, cA, sB, cB;
        __sincosf(0.5f * th, &st, &ct);
        __sincosf(0.5f * (phi + om), &sA, &cA);
        __sincosf(0.5f * (phi - om), &sB, &cB);
        gl4[li][q][0] = make_float4( ct * cA, -ct * sA, -st * cB, -st * sB);
        gl4[li][q][1] = make_float4( st * cB, -st * sB,  ct * cA,  ct * sA);
    }

    // ---- angles = z[samp] @ Win + bin (redundant in both waves) ----
    float ang[NQ];
    {
        const float* zrow = z + (size_t)samp * CDIM;
        f2 a5[NQ / 2];
#pragma unroll
        for (int h = 0; h < NQ / 2; ++h) a5[h] = (f2){0.f, 0.f};
#pragma unroll
        for (int j = 0; j < 3; ++j) {
            const int kb = 4 * (lane + 64 * j);
            const float4 zv = *(const float4*)(zrow + kb);
            float w40[40];
#pragma unroll
            for (int t = 0; t < 10; ++t) {
                const float4 u = *(const float4*)(Win + (size_t)kb * NQ + 4 * t);
                w40[4 * t] = u.x; w40[4 * t + 1] = u.y;
                w40[4 * t + 2] = u.z; w40[4 * t + 3] = u.w;
            }
            const float zc[4] = {zv.x, zv.y, zv.z, zv.w};
#pragma unroll
            for (int c = 0; c < 4; ++c)
#pragma unroll
                for (int h = 0; h < NQ / 2; ++h) {
                    f2 w; w.x = w40[c * 10 + 2 * h]; w.y = w40[c * 10 + 2 * h + 1];
                    a5[h] += w * zc[c];
                }
        }
#pragma unroll
        for (int h = 0; h < NQ / 2; ++h) {
            ang[2 * h]     = wave_sum(a5[h].x) + bin[2 * h];
            ang[2 * h + 1] = wave_sum(a5[h].y) + bin[2 * h + 1];
        }
    }

    __syncthreads();   // gl4 ready

    // ---- fused layer-0 first columns: F_q = Rot(l0,q)*RX(ang_q) ----
    f2 f0[NQ], f1[NQ];
#pragma unroll
    for (int q = 0; q < NQ; ++q) {
        const float4 p0 = gl4[0][q][0];
        const float4 p1 = gl4[0][q][1];
        float s, c;
        __sincosf(0.5f * ang[q], &s, &c);
        f2 a, b;
        a.x = p0.x * c + s * p0.w;  a.y = p0.y * c - s * p0.z;
        b.x = p1.x * c + s * p1.w;  b.y = p1.y * c - s * p1.z;
        f0[q] = a; f1[q] = b;
    }

    // ---- product state POST-ring-0 (ring 0 absorbed) ----
    // x_j = y_j^y_{j+1} (j=0..7), x8 = y0^y8^y9, x9 = y0^y9
    // y0..y5 = lane bits, y6..y8 = reg bits r0..r2, y9 = hs. Wire w <-> x_{9-w}.
    const int gray = lane ^ (lane >> 1);
    const int l5  = (lane >> 5) & 1;
    const int l0h = (lane & 1) ^ hs;
    f2 G0 = ((gray >> 0) & 1) ? f1[9] : f0[9];
    f2 G1 = ((gray >> 1) & 1) ? f1[8] : f0[8];
    f2 G2 = ((gray >> 2) & 1) ? f1[7] : f0[7];
    f2 G3 = ((gray >> 3) & 1) ? f1[6] : f0[6];
    f2 G4 = ((gray >> 4) & 1) ? f1[5] : f0[5];
    f2 L5 = cmul(cmul(G0, G1), cmul(G2, cmul(G3, G4)));
    L5 = cmul(L5, l0h ? f1[0] : f0[0]);          // wire 0: x9 = l0^hs (uniform)
    f2 B5[2];                                    // wire 4: x5 = l5^r0
    B5[0] = l5 ? f1[4] : f0[4];
    B5[1] = l5 ? f0[4] : f1[4];
    f2 D8[2];                                    // wire 1: x8 = l0^hs^r2
    D8[0] = l0h ? f1[1] : f0[1];
    D8[1] = l0h ? f0[1] : f1[1];

    f2 P1[2];
    P1[0] = cmul(L5, B5[0]);
    P1[1] = cmul(L5, B5[1]);
    f2 P2[4];   // r0 + 2*r1; wire 3: x6 = r0^r1
#pragma unroll
    for (int r1b = 0; r1b < 2; ++r1b)
#pragma unroll
        for (int r0b = 0; r0b < 2; ++r0b)
            P2[r0b + 2 * r1b] = cmul(P1[r0b], (r0b ^ r1b) ? f1[3] : f0[3]);
    f2 P3[8];   // + 4*r2; wire 2: x7 = r1^r2
#pragma unroll
    for (int r2b = 0; r2b < 2; ++r2b)
#pragma unroll
        for (int p = 0; p < 4; ++p)
            P3[p + 4 * r2b] = cmul(P2[p], (((p >> 1) & 1) ^ r2b) ? f1[2] : f0[2]);

    f2 v[NR];
#pragma unroll
    for (int r = 0; r < NR; ++r) v[r] = cmul(P3[r], D8[(r >> 2) & 1]);

    // ---- layers 1..2 (rings 0,2 absorbed; ring 1 explicit) ----
#pragma unroll 1
    for (int l = 0; l < 2; ++l) {
        rot_wave_gate(v, lane, hs, mybuf, pbuf, &gl4[l + 1][0][0]);  // wire 0
        rot_layer_rest(v, lane, &gl4[l + 1][0][0]);                  // wires 1..9
        if (l == 0) cnot_ring1(v, lane, hs, mybuf, pbuf);
    }

    // ---- expectation values (partials over own half) ----
    float pr[NR];
#pragma unroll
    for (int r = 0; r < NR; ++r) pr[r] = v[r].x * v[r].x + v[r].y * v[r].y;

    float ev[NQ];
    measure_all(pr, lane, hs, ev);

    if (lane == 0) {
#pragma unroll
        for (int w = 0; w < NQ; ++w) sev[wave][w] = ev[w];
    }
    __syncthreads();
#pragma unroll
    for (int w = 0; w < NQ; ++w) ev[w] += sev[wave ^ 1][w];

    // ---- out[samp] = ev @ Wout + bout (384 columns per wave) ----
#pragma unroll 1
    for (int it = 0; it < 3; ++it) {
        const int d0 = hs * 384 + it * 128 + lane * 2;
        f2 w2[NQ];
#pragma unroll
        for (int q = 0; q < NQ; ++q) w2[q] = *(const f2*)(Wout + q * CDIM + d0);
        f2 o = *(const f2*)(bout + d0);
#pragma unroll
        for (int q = 0; q < NQ; ++q) o += w2[q] * ev[q];
        *(f2*)(out + (size_t)samp * CDIM + d0) = o;
    }
}

extern "C" void kernel_launch(void* const* d_in, const int* in_sizes, int n_in,
                              void* d_out, int out_size, void* d_ws, size_t ws_size,
                              hipStream_t stream) {
    const float* z    = (const float*)d_in[0];
    const float* Win  = (const float*)d_in[1];
    const float* bin  = (const float*)d_in[2];
    const float* wts  = (const float*)d_in[3];
    const float* Wout = (const float*)d_in[4];
    const float* bout = (const float*)d_in[5];
    float* outp       = (float*)d_out;

    const int batch = in_sizes[0] / CDIM;   // 2048
    qembed<<<batch, 128, 0, stream>>>(z, Win, bin, wts, Wout, bout, outp);
}

// Round 16
// 24.234 us; speedup vs baseline: 1.2410x; 1.2410x over previous
//
#include <hip/hip_runtime.h>

typedef float f2 __attribute__((ext_vector_type(2)));   // packed PAIR OF SAMPLES
typedef float f4 __attribute__((ext_vector_type(4)));

constexpr int NQ   = 10;
constexpr int CDIM = 768;
constexpr int NL   = 3;
constexpr int NREG = 16;   // index bits 6..9 in the register index
constexpr int WPB  = 4;    // waves per block; each wave = 2 samples

// ---------- cross-lane primitives (all VALU, no LDS pipe) ----------

template<int CTRL>
__device__ __forceinline__ float dppmov(float x) {
    return __int_as_float(__builtin_amdgcn_update_dpp(
        __float_as_int(x), __float_as_int(x), CTRL, 0xF, 0xF, true));
}

template<int MASK>
__device__ __forceinline__ float lxor(float x, int lane) {
    static_assert(MASK == 1 || MASK == 2 || MASK == 4 || MASK == 8, "");
    if constexpr (MASK == 1)      return dppmov<0xB1>(x);   // quad_perm [1,0,3,2]
    else if constexpr (MASK == 2) return dppmov<0x4E>(x);   // quad_perm [2,3,0,1]
    else if constexpr (MASK == 4) {
        const float a = dppmov<0x104>(x);   // row_shl:4 -> src[i+4] (bit2=0)
        const float b = dppmov<0x114>(x);   // row_shr:4 -> src[i-4] (bit2=1)
        return ((lane >> 2) & 1) ? b : a;
    }
    else                          return dppmov<0x128>(x);  // row_ror:8 == xor8
}

template<int MASK>
__device__ __forceinline__ f2 lxor2(f2 x, int lane) {
    f2 r;
    r.x = lxor<MASK>(x.x, lane);
    r.y = lxor<MASK>(x.y, lane);
    return r;
}

template<int B>
__device__ __forceinline__ void swap2(float x, float& lo, float& hi) {
    const unsigned xu = __float_as_uint(x);
#if __has_builtin(__builtin_amdgcn_permlane16_swap) && __has_builtin(__builtin_amdgcn_permlane32_swap)
    if constexpr (B == 4) {
        auto r = __builtin_amdgcn_permlane16_swap(xu, xu, false, false);
        lo = __uint_as_float(r[0]); hi = __uint_as_float(r[1]);
    } else {
        auto r = __builtin_amdgcn_permlane32_swap(xu, xu, false, false);
        lo = __uint_as_float(r[0]); hi = __uint_as_float(r[1]);
    }
#else
    float d, s;
    if constexpr (B == 4)
        asm("v_mov_b32 %0, %2\n\tv_mov_b32 %1, %2\n\ts_nop 1\n\t"
            "v_permlane16_swap_b32 %0, %1" : "=&v"(d), "=&v"(s) : "v"(x));
    else
        asm("v_mov_b32 %0, %2\n\tv_mov_b32 %1, %2\n\ts_nop 1\n\t"
            "v_permlane32_swap_b32 %0, %1" : "=&v"(d), "=&v"(s) : "v"(x));
    lo = d; hi = s;
#endif
}

// vector-component-safe wrapper: locals only (refs can't bind to vec elems)
template<int B>
__device__ __forceinline__ void swap2v(f2 x, f2& lo, f2& hi) {
    float lx, hx, ly, hy;
    swap2<B>(x.x, lx, hx);
    swap2<B>(x.y, ly, hy);
    lo.x = lx; lo.y = ly;
    hi.x = hx; hi.y = hy;
}

__device__ __forceinline__ float wave_sum(float v) {
    v += dppmov<0xB1>(v);
    v += dppmov<0x4E>(v);
    v += dppmov<0x141>(v);   // row_half_mirror = xor7 (bits 0-1 uniform)
    v += dppmov<0x140>(v);   // row_mirror = xor15
    float lo, hi;
    swap2<4>(v, lo, hi); v = lo + hi;
    swap2<5>(v, lo, hi); v = lo + hi;
    return v;
}

__device__ __forceinline__ f2 wave_sum2(f2 v) {
    f2 r;
    r.x = wave_sum(v.x);
    r.y = wave_sum(v.y);
    return r;
}

// ---------- packed-pair complex helpers ----------
// c2: one complex amplitude for TWO samples (re = (s0,s1), im = (s0,s1)).
// Gate coefficients are wave-uniform complex scalars g = (gx, gy).

struct c2 { f2 re, im; };

__device__ __forceinline__ c2 cmulP(f2 g, c2 a) {
    c2 r;
    r.re = a.re * g.x - a.im * g.y;
    r.im = a.im * g.x + a.re * g.y;
    return r;
}
__device__ __forceinline__ c2 cfmaP(f2 g, c2 a, c2 acc) {
    acc.re += a.re * g.x - a.im * g.y;
    acc.im += a.im * g.x + a.re * g.y;
    return acc;
}

// scalar (single-sample) complex for the layer-0 tree
__device__ __forceinline__ f2 swapneg(f2 b) { f2 r; r.x = -b.y; r.y = b.x; return r; }
__device__ __forceinline__ f2 cmul(f2 a, f2 b) { return b * a.x + swapneg(b) * a.y; }

// ---------- 1-qubit gate on index-bit B, packed pair ----------

template<int B>
__device__ __forceinline__ void gate_bit(c2 (&v)[NREG], int lane,
                                         f2 g00, f2 g01, f2 g10, f2 g11) {
    if constexpr (B >= 6) {                       // register bit: pure in-reg
        constexpr int rb = B - 6;
#pragma unroll
        for (int p = 0; p < NREG / 2; ++p) {
            const int r0 = ((p >> rb) << (rb + 1)) | (p & ((1 << rb) - 1));
            const int r1 = r0 | (1 << rb);
            const c2 a0 = v[r0], a1 = v[r1];
            v[r0] = cfmaP(g01, a1, cmulP(g00, a0));
            v[r1] = cfmaP(g11, a1, cmulP(g10, a0));
        }
    } else if constexpr (B >= 4) {                // lane bit via permlane swap
        const bool hb = (lane >> B) & 1;
        const f2 A  = hb ? g10 : g00;
        const f2 Bc = hb ? g11 : g01;
#pragma unroll
        for (int r = 0; r < NREG; ++r) {
            c2 lo, hi;
            swap2v<B>(v[r].re, lo.re, hi.re);
            swap2v<B>(v[r].im, lo.im, hi.im);
            v[r] = cfmaP(Bc, hi, cmulP(A, lo));
        }
    } else {                                      // lane bit via DPP
        const bool hb = (lane >> B) & 1;
        const f2 cO = hb ? g11 : g00;
        const f2 cP = hb ? g10 : g01;
#pragma unroll
        for (int r = 0; r < NREG; ++r) {
            c2 p;
            p.re = lxor2<(1 << B)>(v[r].re, lane);
            p.im = lxor2<(1 << B)>(v[r].im, lane);
            v[r] = cfmaP(cP, p, cmulP(cO, v[r]));
        }
    }
}

template<int BT>
__device__ __forceinline__ f2 partner2(f2 x, int lane) {
    if constexpr (BT >= 4) {
        f2 lo, hi;
        swap2v<BT>(x, lo, hi);
        f2 r;
        r.x = ((lane >> BT) & 1) ? lo.x : hi.x;
        r.y = ((lane >> BT) & 1) ? lo.y : hi.y;
        return r;
    } else return lxor2<(1 << BT)>(x, lane);
}

// ---------- CNOT (packed pair) ----------

template<int BC, int BT>
__device__ __forceinline__ void cnot(c2 (&v)[NREG], int lane) {
    if constexpr (BC >= 6 && BT >= 6) {           // both reg: free rename
        constexpr int rc = BC - 6, rt = BT - 6;
#pragma unroll
        for (int r = 0; r < NREG; ++r)
            if (((r >> rc) & 1) && !((r >> rt) & 1)) {
                const int r1 = r | (1 << rt);
                const c2 t = v[r]; v[r] = v[r1]; v[r1] = t;
            }
    } else if constexpr (BC >= 6) {               // reg control, lane target
        constexpr int rc = BC - 6;
#pragma unroll
        for (int r = 0; r < NREG; ++r)
            if ((r >> rc) & 1) {
                c2 n;
                n.re = partner2<BT>(v[r].re, lane);
                n.im = partner2<BT>(v[r].im, lane);
                v[r] = n;
            }
    } else if constexpr (BT >= 6) {               // lane control, reg target
        constexpr int rt = BT - 6;
        const bool c = (lane >> BC) & 1;
#pragma unroll
        for (int p = 0; p < NREG / 2; ++p) {
            const int r0 = ((p >> rt) << (rt + 1)) | (p & ((1 << rt) - 1));
            const int r1 = r0 | (1 << rt);
            const c2 a = v[r0], b = v[r1];
            v[r0].re = c ? b.re : a.re;  v[r0].im = c ? b.im : a.im;
            v[r1].re = c ? a.re : b.re;  v[r1].im = c ? a.im : b.im;
        }
    } else {                                      // both lane
        const bool c = (lane >> BC) & 1;
#pragma unroll
        for (int r = 0; r < NREG; ++r) {
            const f2 pre = partner2<BT>(v[r].re, lane);
            const f2 pim = partner2<BT>(v[r].im, lane);
            v[r].re = c ? pre : v[r].re;
            v[r].im = c ? pim : v[r].im;
        }
    }
}

// ---------- rot layer from LDS matrices (code emitted ONCE, looped) ----------

template<int Q = 0>
__device__ __forceinline__ void rot_layer_lds(c2 (&v)[NREG], int lane,
                                              const float4* g /*LDS [NQ][2]*/) {
    if constexpr (Q < NQ) {
        const float4 p0 = g[Q * 2];        // broadcast ds_read_b128
        const float4 p1 = g[Q * 2 + 1];
        f2 g00 = {p0.x, p0.y}, g01 = {p0.z, p0.w};
        f2 g10 = {p1.x, p1.y}, g11 = {p1.z, p1.w};
        gate_bit<9 - Q>(v, lane, g00, g01, g10, g11);
        rot_layer_lds<Q + 1>(v, lane, g);
    }
}

template<int L, int I = 0>
__device__ __forceinline__ void cnot_ring(c2 (&v)[NREG], int lane) {
    if constexpr (I < NQ) {
        constexpr int R = (L % (NQ - 1)) + 1;
        cnot<9 - I, 9 - ((I + R) % NQ)>(v, lane);
        cnot_ring<L, I + 1>(v, lane);
    }
}

// ---------- ring-2 absorbed measurement ----------
constexpr unsigned ring2_mask(int w) {
    unsigned M[NQ] = {};
    for (int i = 0; i < NQ; ++i) M[i] = 1u << (9 - i);
    for (int i = 0; i < NQ; ++i) M[(i + 3) % NQ] ^= M[i];
    return M[w];
}

template<unsigned MR>
__device__ __forceinline__ f2 regsum16(const f2 (&pr)[NREG]) {
    f2 s = {0.f, 0.f};
#pragma unroll
    for (int r = 0; r < NREG; ++r)
        s = (__builtin_popcount((unsigned)r & MR) & 1) ? s - pr[r] : s + pr[r];
    return s;
}

template<int W = 0>
__device__ __forceinline__ void measure_all(const f2 (&pr)[NREG], int lane,
                                            f2 (&ev)[NQ]) {
    if constexpr (W < NQ) {
        constexpr unsigned m  = ring2_mask(W);
        constexpr unsigned mr = (m >> 6) & 0xFu;
        constexpr unsigned ml = m & 63u;
        f2 s = regsum16<mr>(pr);
        if constexpr (ml != 0) {
            const unsigned flip = (unsigned)((__popc(lane & (int)ml) & 1)) << 31;
            s.x = __uint_as_float(__float_as_uint(s.x) ^ flip);
            s.y = __uint_as_float(__float_as_uint(s.y) ^ flip);
        }
        ev[W] = wave_sum2(s);
        measure_all<W + 1>(pr, lane, ev);
    }
}

// ---------- main kernel: 2 samples per wave ----------
__global__ __launch_bounds__(64 * WPB, 1) void qembed(
    const float* __restrict__ z,     // (B, CDIM)
    const float* __restrict__ Win,   // (CDIM, NQ)
    const float* __restrict__ bin,   // (NQ)
    const float* __restrict__ wts,   // (NL, NQ, 3)
    const float* __restrict__ Wout,  // (NQ, CDIM)
    const float* __restrict__ bout,  // (CDIM)
    float* __restrict__ out)         // (B, CDIM)
{
    __shared__ float4 gl4[NL][NQ][2];   // all 3 layers' gate matrices (960 B)

    const int wave  = threadIdx.x >> 6;
    const int lane  = threadIdx.x & 63;
    const int samp0 = (blockIdx.x * WPB + wave) * 2;   // pair: samp0, samp0+1

    // ---- 30 threads build all gate matrices once per block ----
    if (threadIdx.x < NL * NQ) {
        const int li = threadIdx.x / NQ, q = threadIdx.x % NQ;
        const float* wp = wts + (li * NQ + q) * 3;
        const float phi = wp[0], th = wp[1], om = wp[2];
        float st, ct, sA, cA, sB, cB;
        __sincosf(0.5f * th, &st, &ct);
        __sincosf(0.5f * (phi + om), &sA, &cA);
        __sincosf(0.5f * (phi - om), &sB, &cB);
        gl4[li][q][0] = make_float4( ct * cA, -ct * sA, -st * cB, -st * sB);
        gl4[li][q][1] = make_float4( st * cB, -st * sB,  ct * cA,  ct * sA);
    }

    // ---- angles (both samples): packed z pair, shared Win loads ----
    f2 ang[NQ];
    {
        const float* z0 = z + (size_t)samp0 * CDIM;
        const float* z1 = z0 + CDIM;
        f2 acc[NQ];
#pragma unroll
        for (int q = 0; q < NQ; ++q) acc[q] = (f2){0.f, 0.f};
#pragma unroll
        for (int j = 0; j < 3; ++j) {
            const int kb = 4 * (lane + 64 * j);
            const float4 za = *(const float4*)(z0 + kb);
            const float4 zb = *(const float4*)(z1 + kb);
            float w40[40];
#pragma unroll
            for (int t = 0; t < 10; ++t) {
                const float4 u = *(const float4*)(Win + (size_t)kb * NQ + 4 * t);
                w40[4 * t] = u.x; w40[4 * t + 1] = u.y;
                w40[4 * t + 2] = u.z; w40[4 * t + 3] = u.w;
            }
            const float za4[4] = {za.x, za.y, za.z, za.w};
            const float zb4[4] = {zb.x, zb.y, zb.z, zb.w};
#pragma unroll
            for (int c = 0; c < 4; ++c) {
                f2 zp; zp.x = za4[c]; zp.y = zb4[c];
#pragma unroll
                for (int q = 0; q < NQ; ++q) acc[q] += zp * w40[c * 10 + q];
            }
        }
#pragma unroll
        for (int q = 0; q < NQ; ++q) ang[q] = wave_sum2(acc[q]) + bin[q];
    }

    __syncthreads();   // gl4 ready

    // ---- layer 0 + ring 0 absorbed: per-sample product tree -> packed v ----
    c2 v[NREG];
#pragma unroll
    for (int s = 0; s < 2; ++s) {
        // fused F_q = Rot(l0,q)*RX(ang_q) first columns, sample s
        f2 f0[NQ], f1[NQ];
#pragma unroll
        for (int q = 0; q < NQ; ++q) {
            const float4 p0 = gl4[0][q][0];
            const float4 p1 = gl4[0][q][1];
            const float aq = s ? ang[q].y : ang[q].x;
            float sn, cs;
            __sincosf(0.5f * aq, &sn, &cs);
            f2 a, b;
            a.x = p0.x * cs + sn * p0.w;  a.y = p0.y * cs - sn * p0.z;
            b.x = p1.x * cs + sn * p1.w;  b.y = p1.y * cs - sn * p1.z;
            f0[q] = a; f1[q] = b;
        }
        // ring-0 absorbed product state (x_j = y_j^y_{j+1} j=0..7,
        // x8 = y0^y8^y9, x9 = y0^y9); y0..5 lane, y6..9 reg.
        const int gray = lane ^ (lane >> 1);
        const int l0 = lane & 1;
        const int l5 = (lane >> 5) & 1;
        f2 G0 = ((gray >> 0) & 1) ? f1[9] : f0[9];
        f2 G1 = ((gray >> 1) & 1) ? f1[8] : f0[8];
        f2 G2 = ((gray >> 2) & 1) ? f1[7] : f0[7];
        f2 G3 = ((gray >> 3) & 1) ? f1[6] : f0[6];
        f2 G4 = ((gray >> 4) & 1) ? f1[5] : f0[5];
        const f2 L5 = cmul(cmul(G0, G1), cmul(G2, cmul(G3, G4)));
        f2 B5[2];
        B5[0] = l5 ? f1[4] : f0[4];
        B5[1] = l5 ? f0[4] : f1[4];
        f2 D8[2], E9[2];
        D8[0] = l0 ? f1[1] : f0[1];
        D8[1] = l0 ? f0[1] : f1[1];
        E9[0] = l0 ? f1[0] : f0[0];
        E9[1] = l0 ? f0[0] : f1[0];

        f2 P1[2];
        P1[0] = cmul(L5, B5[0]);
        P1[1] = cmul(L5, B5[1]);
        f2 P2[4];
#pragma unroll
        for (int r1b = 0; r1b < 2; ++r1b)
#pragma unroll
            for (int r0b = 0; r0b < 2; ++r0b)
                P2[r0b + 2 * r1b] = cmul(P1[r0b], (r0b ^ r1b) ? f1[3] : f0[3]);
        f2 P3[8];
#pragma unroll
        for (int r2b = 0; r2b < 2; ++r2b)
#pragma unroll
            for (int p = 0; p < 4; ++p)
                P3[p + 4 * r2b] = cmul(P2[p], (((p >> 1) & 1) ^ r2b) ? f1[2] : f0[2]);
        f2 W[4];
#pragma unroll
        for (int d = 0; d < 2; ++d)
#pragma unroll
            for (int u = 0; u < 2; ++u)
                W[u + 2 * d] = cmul(D8[u], E9[d]);

#pragma unroll
        for (int r = 0; r < NREG; ++r) {
            const int r2b = (r >> 2) & 1, r3b = (r >> 3) & 1;
            const f2 amp = cmul(P3[r & 7], W[(r2b ^ r3b) + 2 * r3b]);
            if (s == 0) { v[r].re.x = amp.x; v[r].im.x = amp.y; }
            else        { v[r].re.y = amp.x; v[r].im.y = amp.y; }
        }
    }

    // ---- layers 1..2 from LDS (code once); rings 0,2 absorbed ----
#pragma unroll 1
    for (int l = 0; l < 2; ++l) {
        rot_layer_lds(v, lane, &gl4[l + 1][0][0]);
        if (l == 0) cnot_ring<1>(v, lane);
    }

    // ---- expectation values with ring-2 parity masks (both samples) ----
    f2 pr[NREG];
#pragma unroll
    for (int r = 0; r < NREG; ++r)
        pr[r] = v[r].re * v[r].re + v[r].im * v[r].im;

    f2 ev[NQ];
    measure_all(pr, lane, ev);

    // ---- out = ev @ Wout + bout, both samples, shared Wout loads ----
#pragma unroll 1
    for (int ch = 0; ch < 3; ++ch) {
        const int d0 = ch * 256 + lane * 4;
        f4 w4[NQ];
#pragma unroll
        for (int q = 0; q < NQ; ++q) w4[q] = *(const f4*)(Wout + q * CDIM + d0);
        const f4 bo = *(const f4*)(bout + d0);
        f4 o0 = bo, o1 = bo;
#pragma unroll
        for (int q = 0; q < NQ; ++q) {
            o0 += w4[q] * ev[q].x;
            o1 += w4[q] * ev[q].y;
        }
        *(f4*)(out + (size_t)samp0 * CDIM + d0) = o0;
        *(f4*)(out + (size_t)(samp0 + 1) * CDIM + d0) = o1;
    }
}

extern "C" void kernel_launch(void* const* d_in, const int* in_sizes, int n_in,
                              void* d_out, int out_size, void* d_ws, size_t ws_size,
                              hipStream_t stream) {
    const float* z    = (const float*)d_in[0];
    const float* Win  = (const float*)d_in[1];
    const float* bin  = (const float*)d_in[2];
    const float* wts  = (const float*)d_in[3];
    const float* Wout = (const float*)d_in[4];
    const float* bout = (const float*)d_in[5];
    float* outp       = (float*)d_out;

    const int batch  = in_sizes[0] / CDIM;      // 2048
    const int blocks = batch / (2 * WPB);       // 256 (2 samples per wave)
    qembed<<<blocks, 64 * WPB, 0, stream>>>(z, Win, bin, wts, Wout, bout, outp);
}

// Round 17
// 24.051 us; speedup vs baseline: 1.2504x; 1.0076x over previous
//
#include <hip/hip_runtime.h>

typedef float f2 __attribute__((ext_vector_type(2)));   // packed PAIR OF SAMPLES
typedef float f4 __attribute__((ext_vector_type(4)));

constexpr int NQ   = 10;
constexpr int CDIM = 768;
constexpr int NL   = 3;
constexpr int NREG = 16;   // index bits 6..9 in the register index
constexpr int WPB  = 4;    // waves per block; each wave = 2 samples

// ---------- cross-lane primitives (all VALU, no LDS pipe) ----------

template<int CTRL>
__device__ __forceinline__ float dppmov(float x) {
    return __int_as_float(__builtin_amdgcn_update_dpp(
        __float_as_int(x), __float_as_int(x), CTRL, 0xF, 0xF, true));
}

template<int MASK>
__device__ __forceinline__ float lxor(float x, int lane) {
    static_assert(MASK == 1 || MASK == 2 || MASK == 4 || MASK == 8, "");
    if constexpr (MASK == 1)      return dppmov<0xB1>(x);   // quad_perm [1,0,3,2]
    else if constexpr (MASK == 2) return dppmov<0x4E>(x);   // quad_perm [2,3,0,1]
    else if constexpr (MASK == 4) {
        const float a = dppmov<0x104>(x);   // row_shl:4 -> src[i+4] (bit2=0)
        const float b = dppmov<0x114>(x);   // row_shr:4 -> src[i-4] (bit2=1)
        return ((lane >> 2) & 1) ? b : a;
    }
    else                          return dppmov<0x128>(x);  // row_ror:8 == xor8
}

template<int MASK>
__device__ __forceinline__ f2 lxor2(f2 x, int lane) {
    f2 r;
    r.x = lxor<MASK>(x.x, lane);
    r.y = lxor<MASK>(x.y, lane);
    return r;
}

template<int B>
__device__ __forceinline__ void swap2(float x, float& lo, float& hi) {
    const unsigned xu = __float_as_uint(x);
#if __has_builtin(__builtin_amdgcn_permlane16_swap) && __has_builtin(__builtin_amdgcn_permlane32_swap)
    if constexpr (B == 4) {
        auto r = __builtin_amdgcn_permlane16_swap(xu, xu, false, false);
        lo = __uint_as_float(r[0]); hi = __uint_as_float(r[1]);
    } else {
        auto r = __builtin_amdgcn_permlane32_swap(xu, xu, false, false);
        lo = __uint_as_float(r[0]); hi = __uint_as_float(r[1]);
    }
#else
    float d, s;
    if constexpr (B == 4)
        asm("v_mov_b32 %0, %2\n\tv_mov_b32 %1, %2\n\ts_nop 1\n\t"
            "v_permlane16_swap_b32 %0, %1" : "=&v"(d), "=&v"(s) : "v"(x));
    else
        asm("v_mov_b32 %0, %2\n\tv_mov_b32 %1, %2\n\ts_nop 1\n\t"
            "v_permlane32_swap_b32 %0, %1" : "=&v"(d), "=&v"(s) : "v"(x));
    lo = d; hi = s;
#endif
}

// vector-component-safe wrapper: locals only (refs can't bind to vec elems)
template<int B>
__device__ __forceinline__ void swap2v(f2 x, f2& lo, f2& hi) {
    float lx, hx, ly, hy;
    swap2<B>(x.x, lx, hx);
    swap2<B>(x.y, ly, hy);
    lo.x = lx; lo.y = ly;
    hi.x = hx; hi.y = hy;
}

__device__ __forceinline__ float wave_sum(float v) {
    v += dppmov<0xB1>(v);
    v += dppmov<0x4E>(v);
    v += dppmov<0x141>(v);   // row_half_mirror = xor7 (bits 0-1 uniform)
    v += dppmov<0x140>(v);   // row_mirror = xor15
    float lo, hi;
    swap2<4>(v, lo, hi); v = lo + hi;
    swap2<5>(v, lo, hi); v = lo + hi;
    return v;
}

__device__ __forceinline__ f2 wave_sum2(f2 v) {
    f2 r;
    r.x = wave_sum(v.x);
    r.y = wave_sum(v.y);
    return r;
}

// ---------- packed-pair complex helpers ----------
// c2: one complex amplitude for TWO samples (re = (s0,s1), im = (s0,s1)).

struct c2 { f2 re, im; };

__device__ __forceinline__ c2 cmulP(f2 g, c2 a) {
    c2 r;
    r.re = a.re * g.x - a.im * g.y;
    r.im = a.im * g.x + a.re * g.y;
    return r;
}
__device__ __forceinline__ c2 cfmaP(f2 g, c2 a, c2 acc) {
    acc.re += a.re * g.x - a.im * g.y;
    acc.im += a.im * g.x + a.re * g.y;
    return acc;
}

// scalar (single-sample) complex for the layer-0 tree
__device__ __forceinline__ f2 swapneg(f2 b) { f2 r; r.x = -b.y; r.y = b.x; return r; }
__device__ __forceinline__ f2 cmul(f2 a, f2 b) { return b * a.x + swapneg(b) * a.y; }

// ---------- 1-qubit gate on index-bit B, packed pair ----------

template<int B>
__device__ __forceinline__ void gate_bit(c2 (&v)[NREG], int lane,
                                         f2 g00, f2 g01, f2 g10, f2 g11) {
    if constexpr (B >= 6) {                       // register bit: pure in-reg
        constexpr int rb = B - 6;
#pragma unroll
        for (int p = 0; p < NREG / 2; ++p) {
            const int r0 = ((p >> rb) << (rb + 1)) | (p & ((1 << rb) - 1));
            const int r1 = r0 | (1 << rb);
            const c2 a0 = v[r0], a1 = v[r1];
            v[r0] = cfmaP(g01, a1, cmulP(g00, a0));
            v[r1] = cfmaP(g11, a1, cmulP(g10, a0));
        }
    } else if constexpr (B >= 4) {                // lane bit via permlane swap
        const bool hb = (lane >> B) & 1;
        const f2 A  = hb ? g10 : g00;
        const f2 Bc = hb ? g11 : g01;
#pragma unroll
        for (int r = 0; r < NREG; ++r) {
            c2 lo, hi;
            swap2v<B>(v[r].re, lo.re, hi.re);
            swap2v<B>(v[r].im, lo.im, hi.im);
            v[r] = cfmaP(Bc, hi, cmulP(A, lo));
        }
    } else {                                      // lane bit via DPP
        const bool hb = (lane >> B) & 1;
        const f2 cO = hb ? g11 : g00;
        const f2 cP = hb ? g10 : g01;
#pragma unroll
        for (int r = 0; r < NREG; ++r) {
            c2 p;
            p.re = lxor2<(1 << B)>(v[r].re, lane);
            p.im = lxor2<(1 << B)>(v[r].im, lane);
            v[r] = cfmaP(cP, p, cmulP(cO, v[r]));
        }
    }
}

template<int BT>
__device__ __forceinline__ f2 partner2(f2 x, int lane) {
    if constexpr (BT >= 4) {
        f2 lo, hi;
        swap2v<BT>(x, lo, hi);
        f2 r;
        r.x = ((lane >> BT) & 1) ? lo.x : hi.x;
        r.y = ((lane >> BT) & 1) ? lo.y : hi.y;
        return r;
    } else return lxor2<(1 << BT)>(x, lane);
}

// ---------- CNOT (packed pair) ----------

template<int BC, int BT>
__device__ __forceinline__ void cnot(c2 (&v)[NREG], int lane) {
    if constexpr (BC >= 6 && BT >= 6) {           // both reg: free rename
        constexpr int rc = BC - 6, rt = BT - 6;
#pragma unroll
        for (int r = 0; r < NREG; ++r)
            if (((r >> rc) & 1) && !((r >> rt) & 1)) {
                const int r1 = r | (1 << rt);
                const c2 t = v[r]; v[r] = v[r1]; v[r1] = t;
            }
    } else if constexpr (BC >= 6) {               // reg control, lane target
        constexpr int rc = BC - 6;
#pragma unroll
        for (int r = 0; r < NREG; ++r)
            if ((r >> rc) & 1) {
                c2 n;
                n.re = partner2<BT>(v[r].re, lane);
                n.im = partner2<BT>(v[r].im, lane);
                v[r] = n;
            }
    } else if constexpr (BT >= 6) {               // lane control, reg target
        constexpr int rt = BT - 6;
        const bool c = (lane >> BC) & 1;
#pragma unroll
        for (int p = 0; p < NREG / 2; ++p) {
            const int r0 = ((p >> rt) << (rt + 1)) | (p & ((1 << rt) - 1));
            const int r1 = r0 | (1 << rt);
            const c2 a = v[r0], b = v[r1];
            v[r0].re = c ? b.re : a.re;  v[r0].im = c ? b.im : a.im;
            v[r1].re = c ? a.re : b.re;  v[r1].im = c ? a.im : b.im;
        }
    } else {                                      // both lane
        const bool c = (lane >> BC) & 1;
#pragma unroll
        for (int r = 0; r < NREG; ++r) {
            const f2 pre = partner2<BT>(v[r].re, lane);
            const f2 pim = partner2<BT>(v[r].im, lane);
            v[r].re = c ? pre : v[r].re;
            v[r].im = c ? pim : v[r].im;
        }
    }
}

// ---------- rot layer: batch-load the layer's matrices LDS->regs first ----------

template<int Q = 0>
__device__ __forceinline__ void rot_layer_arr(c2 (&v)[NREG], int lane,
                                              const float4 (&g)[NQ * 2]) {
    if constexpr (Q < NQ) {
        const float4 p0 = g[Q * 2];
        const float4 p1 = g[Q * 2 + 1];
        f2 g00 = {p0.x, p0.y}, g01 = {p0.z, p0.w};
        f2 g10 = {p1.x, p1.y}, g11 = {p1.z, p1.w};
        gate_bit<9 - Q>(v, lane, g00, g01, g10, g11);
        rot_layer_arr<Q + 1>(v, lane, g);
    }
}

__device__ __forceinline__ void rot_layer_lds(c2 (&v)[NREG], int lane,
                                              const float4* g /*LDS [NQ][2]*/) {
    float4 garr[NQ * 2];
#pragma unroll
    for (int i = 0; i < NQ * 2; ++i) garr[i] = g[i];   // batched ds_read_b128
    rot_layer_arr(v, lane, garr);
}

template<int L, int I = 0>
__device__ __forceinline__ void cnot_ring(c2 (&v)[NREG], int lane) {
    if constexpr (I < NQ) {
        constexpr int R = (L % (NQ - 1)) + 1;
        cnot<9 - I, 9 - ((I + R) % NQ)>(v, lane);
        cnot_ring<L, I + 1>(v, lane);
    }
}

// ---------- ring-2 absorbed measurement ----------
constexpr unsigned ring2_mask(int w) {
    unsigned M[NQ] = {};
    for (int i = 0; i < NQ; ++i) M[i] = 1u << (9 - i);
    for (int i = 0; i < NQ; ++i) M[(i + 3) % NQ] ^= M[i];
    return M[w];
}

template<unsigned MR>
__device__ __forceinline__ f2 regsum16(const f2 (&pr)[NREG]) {
    f2 s = {0.f, 0.f};
#pragma unroll
    for (int r = 0; r < NREG; ++r)
        s = (__builtin_popcount((unsigned)r & MR) & 1) ? s - pr[r] : s + pr[r];
    return s;
}

template<int W = 0>
__device__ __forceinline__ void measure_all(const f2 (&pr)[NREG], int lane,
                                            f2 (&ev)[NQ]) {
    if constexpr (W < NQ) {
        constexpr unsigned m  = ring2_mask(W);
        constexpr unsigned mr = (m >> 6) & 0xFu;
        constexpr unsigned ml = m & 63u;
        f2 s = regsum16<mr>(pr);
        if constexpr (ml != 0) {
            const unsigned flip = (unsigned)((__popc(lane & (int)ml) & 1)) << 31;
            s.x = __uint_as_float(__float_as_uint(s.x) ^ flip);
            s.y = __uint_as_float(__float_as_uint(s.y) ^ flip);
        }
        ev[W] = wave_sum2(s);
        measure_all<W + 1>(pr, lane, ev);
    }
}

// ---------- main kernel: 2 samples per wave ----------
__global__ __launch_bounds__(64 * WPB, 1) void qembed(
    const float* __restrict__ z,     // (B, CDIM)
    const float* __restrict__ Win,   // (CDIM, NQ)
    const float* __restrict__ bin,   // (NQ)
    const float* __restrict__ wts,   // (NL, NQ, 3)
    const float* __restrict__ Wout,  // (NQ, CDIM)
    const float* __restrict__ bout,  // (CDIM)
    float* __restrict__ out)         // (B, CDIM)
{
    __shared__ float4 gl4[NL][NQ][2];   // all 3 layers' gate matrices (960 B)

    const int wave  = threadIdx.x >> 6;
    const int lane  = threadIdx.x & 63;
    const int samp0 = (blockIdx.x * WPB + wave) * 2;   // pair: samp0, samp0+1

    // ---- 30 threads build all gate matrices once per block ----
    if (threadIdx.x < NL * NQ) {
        const int li = threadIdx.x / NQ, q = threadIdx.x % NQ;
        const float* wp = wts + (li * NQ + q) * 3;
        const float phi = wp[0], th = wp[1], om = wp[2];
        float st, ct, sA, cA, sB, cB;
        __sincosf(0.5f * th, &st, &ct);
        __sincosf(0.5f * (phi + om), &sA, &cA);
        __sincosf(0.5f * (phi - om), &sB, &cB);
        gl4[li][q][0] = make_float4( ct * cA, -ct * sA, -st * cB, -st * sB);
        gl4[li][q][1] = make_float4( st * cB, -st * sB,  ct * cA,  ct * sA);
    }

    // ---- angles (both samples): packed z pair, shared Win loads ----
    f2 ang[NQ];
    {
        const float* z0 = z + (size_t)samp0 * CDIM;
        const float* z1 = z0 + CDIM;
        f2 acc[NQ];
#pragma unroll
        for (int q = 0; q < NQ; ++q) acc[q] = (f2){0.f, 0.f};
#pragma unroll
        for (int j = 0; j < 3; ++j) {
            const int kb = 4 * (lane + 64 * j);
            const float4 za = *(const float4*)(z0 + kb);
            const float4 zb = *(const float4*)(z1 + kb);
            float w40[40];
#pragma unroll
            for (int t = 0; t < 10; ++t) {
                const float4 u = *(const float4*)(Win + (size_t)kb * NQ + 4 * t);
                w40[4 * t] = u.x; w40[4 * t + 1] = u.y;
                w40[4 * t + 2] = u.z; w40[4 * t + 3] = u.w;
            }
            const float za4[4] = {za.x, za.y, za.z, za.w};
            const float zb4[4] = {zb.x, zb.y, zb.z, zb.w};
#pragma unroll
            for (int c = 0; c < 4; ++c) {
                f2 zp; zp.x = za4[c]; zp.y = zb4[c];
#pragma unroll
                for (int q = 0; q < NQ; ++q) acc[q] += zp * w40[c * 10 + q];
            }
        }
#pragma unroll
        for (int q = 0; q < NQ; ++q) ang[q] = wave_sum2(acc[q]) + bin[q];
    }

    __syncthreads();   // gl4 ready

    // ---- layer 0 + ring 0 absorbed: per-sample product tree -> packed v ----
    c2 v[NREG];
#pragma unroll
    for (int s = 0; s < 2; ++s) {
        // fused F_q = Rot(l0,q)*RX(ang_q) first columns, sample s
        f2 f0[NQ], f1[NQ];
#pragma unroll
        for (int q = 0; q < NQ; ++q) {
            const float4 p0 = gl4[0][q][0];
            const float4 p1 = gl4[0][q][1];
            const float aq = s ? ang[q].y : ang[q].x;
            float sn, cs;
            __sincosf(0.5f * aq, &sn, &cs);
            f2 a, b;
            a.x = p0.x * cs + sn * p0.w;  a.y = p0.y * cs - sn * p0.z;
            b.x = p1.x * cs + sn * p1.w;  b.y = p1.y * cs - sn * p1.z;
            f0[q] = a; f1[q] = b;
        }
        // ring-0 absorbed product state (x_j = y_j^y_{j+1} j=0..7,
        // x8 = y0^y8^y9, x9 = y0^y9); y0..5 lane, y6..9 reg.
        const int gray = lane ^ (lane >> 1);
        const int l0 = lane & 1;
        const int l5 = (lane >> 5) & 1;
        f2 G0 = ((gray >> 0) & 1) ? f1[9] : f0[9];
        f2 G1 = ((gray >> 1) & 1) ? f1[8] : f0[8];
        f2 G2 = ((gray >> 2) & 1) ? f1[7] : f0[7];
        f2 G3 = ((gray >> 3) & 1) ? f1[6] : f0[6];
        f2 G4 = ((gray >> 4) & 1) ? f1[5] : f0[5];
        const f2 L5 = cmul(cmul(G0, G1), cmul(G2, cmul(G3, G4)));
        f2 B5[2];
        B5[0] = l5 ? f1[4] : f0[4];
        B5[1] = l5 ? f0[4] : f1[4];
        f2 D8[2], E9[2];
        D8[0] = l0 ? f1[1] : f0[1];
        D8[1] = l0 ? f0[1] : f1[1];
        E9[0] = l0 ? f1[0] : f0[0];
        E9[1] = l0 ? f0[0] : f1[0];

        f2 P1[2];
        P1[0] = cmul(L5, B5[0]);
        P1[1] = cmul(L5, B5[1]);
        f2 P2[4];
#pragma unroll
        for (int r1b = 0; r1b < 2; ++r1b)
#pragma unroll
            for (int r0b = 0; r0b < 2; ++r0b)
                P2[r0b + 2 * r1b] = cmul(P1[r0b], (r0b ^ r1b) ? f1[3] : f0[3]);
        f2 P3[8];
#pragma unroll
        for (int r2b = 0; r2b < 2; ++r2b)
#pragma unroll
            for (int p = 0; p < 4; ++p)
                P3[p + 4 * r2b] = cmul(P2[p], (((p >> 1) & 1) ^ r2b) ? f1[2] : f0[2]);
        f2 W[4];
#pragma unroll
        for (int d = 0; d < 2; ++d)
#pragma unroll
            for (int u = 0; u < 2; ++u)
                W[u + 2 * d] = cmul(D8[u], E9[d]);

#pragma unroll
        for (int r = 0; r < NREG; ++r) {
            const int r2b = (r >> 2) & 1, r3b = (r >> 3) & 1;
            const f2 amp = cmul(P3[r & 7], W[(r2b ^ r3b) + 2 * r3b]);
            if (s == 0) { v[r].re.x = amp.x; v[r].im.x = amp.y; }
            else        { v[r].re.y = amp.x; v[r].im.y = amp.y; }
        }
    }

    // ---- layers 1..2 (batched gate reads); rings 0,2 absorbed ----
#pragma unroll 1
    for (int l = 0; l < 2; ++l) {
        rot_layer_lds(v, lane, &gl4[l + 1][0][0]);
        if (l == 0) cnot_ring<1>(v, lane);
    }

    // ---- expectation values with ring-2 parity masks (both samples) ----
    f2 pr[NREG];
#pragma unroll
    for (int r = 0; r < NREG; ++r)
        pr[r] = v[r].re * v[r].re + v[r].im * v[r].im;

    // hoist output weights: 33 VMEM in flight during measurement DPP chains
    f4 w4[3][NQ];
    f4 bo[3];
#pragma unroll
    for (int ch = 0; ch < 3; ++ch) {
        const int d0 = ch * 256 + lane * 4;
#pragma unroll
        for (int q = 0; q < NQ; ++q) w4[ch][q] = *(const f4*)(Wout + q * CDIM + d0);
        bo[ch] = *(const f4*)(bout + d0);
    }

    f2 ev[NQ];
    measure_all(pr, lane, ev);

    // ---- out = ev @ Wout + bout, both samples ----
#pragma unroll
    for (int ch = 0; ch < 3; ++ch) {
        const int d0 = ch * 256 + lane * 4;
        f4 o0 = bo[ch], o1 = bo[ch];
#pragma unroll
        for (int q = 0; q < NQ; ++q) {
            o0 += w4[ch][q] * ev[q].x;
            o1 += w4[ch][q] * ev[q].y;
        }
        *(f4*)(out + (size_t)samp0 * CDIM + d0) = o0;
        *(f4*)(out + (size_t)(samp0 + 1) * CDIM + d0) = o1;
    }
}

extern "C" void kernel_launch(void* const* d_in, const int* in_sizes, int n_in,
                              void* d_out, int out_size, void* d_ws, size_t ws_size,
                              hipStream_t stream) {
    const float* z    = (const float*)d_in[0];
    const float* Win  = (const float*)d_in[1];
    const float* bin  = (const float*)d_in[2];
    const float* wts  = (const float*)d_in[3];
    const float* Wout = (const float*)d_in[4];
    const float* bout = (const float*)d_in[5];
    float* outp       = (float*)d_out;

    const int batch  = in_sizes[0] / CDIM;      // 2048
    const int blocks = batch / (2 * WPB);       // 256 (2 samples per wave)
    qembed<<<blocks, 64 * WPB, 0, stream>>>(z, Win, bin, wts, Wout, bout, outp);
}